// Round 1
// baseline (162.376 us; speedup 1.0000x reference)
//
#include <hip/hip_runtime.h>
#include <hip/hip_bf16.h>

// Problem constants
#define B_    4
#define N_TOT 65536
#define M_TOT 32768
#define C_    4
#define DIN_  64
#define DIM_  64
#define SDIM_ 32

typedef __bf16 bf16x8 __attribute__((ext_vector_type(8)));
typedef float  f32x4  __attribute__((ext_vector_type(4)));
// may_alias variants for LDS round-trip (uint2 store / bf16x8 load of same bytes)
typedef bf16x8 bf16x8_a __attribute__((may_alias));
typedef uint2  uint2_a  __attribute__((may_alias));

__device__ __forceinline__ float prelu_f(float x, float a) { return x >= 0.0f ? x : a * x; }

// d_ws layout (bf16 elements):
//   [0,     8192)  Wm_t [64][128]   Wm_t [n][k] = W_merge[k][n]
//   [8192, 40960)  Wms_t[256][128]  Wms_t[n][k] = W_ms  [k][n]
//   [40960,49152)  Wsa_t[64][128]   Wsa_t[n][k] = W_msamp[k][n]
__global__ void prep_weights(const float* __restrict__ Wm,
                             const float* __restrict__ Wms,
                             const float* __restrict__ Wsa,
                             __hip_bfloat16* __restrict__ ws)
{
    int t = blockIdx.x * blockDim.x + threadIdx.x;
    if (t < 8192) {
        int n = t >> 7, k = t & 127;
        ws[t] = __float2bfloat16(Wm[k * 64 + n]);
    } else if (t < 40960) {
        int u = t - 8192; int n = u >> 7, k = u & 127;
        ws[t] = __float2bfloat16(Wms[k * 256 + n]);
    } else if (t < 49152) {
        int u = t - 40960; int n = u >> 7, k = u & 127;
        ws[t] = __float2bfloat16(Wsa[k * 64 + n]);
    }
}

// One wave handles 16 nodes (one (b, m_base..m_base+15) group), fully fused.
// All MFMAs computed swapped: D = W^T x X^T, so D col (lane&15) = row index,
// D rows ((lane>>4)*4+r) = 4 consecutive output features -> b64/dwordx4 stores.
__global__ __launch_bounds__(256, 2) void encoder_fused(
    const float* __restrict__ last,
    const float* __restrict__ sample,
    const int* __restrict__ child_l,
    const int* __restrict__ child_r,
    const int* __restrict__ child_s,
    const __bf16* __restrict__ wt,
    const float* __restrict__ b_merge, const float* __restrict__ a_merge_p,
    const float* __restrict__ b_ms,    const float* __restrict__ a_ms_p,
    const float* __restrict__ b_msamp, const float* __restrict__ a_msamp_p,
    float* __restrict__ out)
{
    // per-wave private 16KB LDS tile: y[64 rows][128 bf16 cols], XOR-swizzled
    __shared__ char lds_raw[4][16384];
    const int tid  = threadIdx.x;
    const int lane = tid & 63;
    const int wid  = tid >> 6;
    char* Y = &lds_raw[wid][0];

    const int group  = blockIdx.x * 4 + wid;     // 8192 groups total
    const int b      = group >> 11;              // / (M/16 = 2048)
    const int m_base = (group & 2047) << 4;

    const int g   = lane >> 4;                   // 0..3  (k-subchunk / feature sub-block)
    const int j15 = lane & 15;                   // A: feature row | B: node-row col

    const float a_merge = *a_merge_p;
    const float a_ms    = *a_ms_p;
    const float a_msamp = *a_msamp_p;

    const __bf16* Wm_t  = wt;
    const __bf16* Wms_t = wt + 8192;
    const __bf16* Wsa_t = wt + 40960;

    // ---------------- Stage 1: ans = prelu([lch|rch] @ W_merge + b_merge) ----------------
    bf16x8 wm[4][4];
    f32x4  bm[4];
#pragma unroll
    for (int n = 0; n < 4; ++n) {
        bm[n] = *(const f32x4*)(b_merge + n * 16 + g * 4);
#pragma unroll
        for (int kk = 0; kk < 4; ++kk)
            wm[n][kk] = *(const bf16x8*)(Wm_t + (n * 16 + j15) * 128 + kk * 32 + g * 8);
    }

#pragma unroll
    for (int t = 0; t < 4; ++t) {                // m-tile: y rows t*16 + j15
        const int node_local = t * 4 + (j15 >> 2);
        const int c  = j15 & 3;
        const int m  = m_base + node_local;
        const int cl = child_l[m];
        const int cr = child_r[m];
        const float* lsrc = last + ((size_t)(b * N_TOT + cl) * C_ + c) * DIN_;
        const float* rsrc = last + ((size_t)(b * N_TOT + cr) * C_ + c) * DIN_;

        bf16x8 xf[4];
#pragma unroll
        for (int kk = 0; kk < 4; ++kk) {
            const int k = kk * 32 + g * 8;       // k<64 -> lch, else rch
            const float* src = (k < 64) ? (lsrc + k) : (rsrc + (k - 64));
            f32x4 f0 = *(const f32x4*)(src);
            f32x4 f1 = *(const f32x4*)(src + 4);
            bf16x8 v;
            v[0] = (__bf16)f0[0]; v[1] = (__bf16)f0[1]; v[2] = (__bf16)f0[2]; v[3] = (__bf16)f0[3];
            v[4] = (__bf16)f1[0]; v[5] = (__bf16)f1[1]; v[6] = (__bf16)f1[2]; v[7] = (__bf16)f1[3];
            xf[kk] = v;
        }

        const int row = t * 16 + j15;
        const int swz = (row & 7) << 4;
#pragma unroll
        for (int n = 0; n < 4; ++n) {
            f32x4 acc = {0.f, 0.f, 0.f, 0.f};
#pragma unroll
            for (int kk = 0; kk < 4; ++kk)
                acc = __builtin_amdgcn_mfma_f32_16x16x32_bf16(wm[n][kk], xf[kk], acc, 0, 0, 0);
            union { __bf16 h[4]; uint2 u2; } p;
#pragma unroll
            for (int r = 0; r < 4; ++r)
                p.h[r] = (__bf16)prelu_f(acc[r] + bm[n][r], a_merge);
            const int byte = row * 256 + ((n * 32 + g * 8) ^ swz);
            *(uint2_a*)(Y + byte) = p.u2;
        }
    }

    // ---------------- Stage 2: s' = prelu(s_flat @ W_ms + b_ms) ----------------
    {
        const int m  = m_base + j15;             // D col = node index
        const int cs = child_s[m];
        const float* ssrc = sample + (size_t)(b * N_TOT + cs) * 128;
        bf16x8 sf[4];
#pragma unroll
        for (int kk = 0; kk < 4; ++kk) {
            const int k = kk * 32 + g * 8;
            f32x4 f0 = *(const f32x4*)(ssrc + k);
            f32x4 f1 = *(const f32x4*)(ssrc + k + 4);
            bf16x8 v;
            v[0] = (__bf16)f0[0]; v[1] = (__bf16)f0[1]; v[2] = (__bf16)f0[2]; v[3] = (__bf16)f0[3];
            v[4] = (__bf16)f1[0]; v[5] = (__bf16)f1[1]; v[6] = (__bf16)f1[2]; v[7] = (__bf16)f1[3];
            sf[kk] = v;
        }
#pragma unroll
        for (int n2 = 0; n2 < 16; ++n2) {        // 256 output feats = 16 tiles
            f32x4 acc = {0.f, 0.f, 0.f, 0.f};
#pragma unroll
            for (int kk = 0; kk < 4; ++kk) {
                bf16x8 w = *(const bf16x8*)(Wms_t + (n2 * 16 + j15) * 128 + kk * 32 + g * 8);
                acc = __builtin_amdgcn_mfma_f32_16x16x32_bf16(w, sf[kk], acc, 0, 0, 0);
            }
            f32x4 bb = *(const f32x4*)(b_ms + n2 * 16 + g * 4);
            const int f0i = n2 * 16 + g * 4;     // global feature of acc[0]
            const int row = j15 * 4 + (f0i >> 6);         // node*4 + c
            const int byte = row * 256 + ((128 + (f0i & 63) * 2) ^ ((row & 7) << 4));
            union { __bf16 h[4]; uint2 u2; } p;
#pragma unroll
            for (int r = 0; r < 4; ++r)
                p.h[r] = (__bf16)prelu_f(acc[r] + bb[r], a_ms);
            *(uint2_a*)(Y + byte) = p.u2;
        }
    }

    // ---------------- Stage 3: out = prelu([ans|s'] @ W_msamp + b_msamp) ----------------
    bf16x8 wa[4][4];
    f32x4  ba[4];
#pragma unroll
    for (int n = 0; n < 4; ++n) {
        ba[n] = *(const f32x4*)(b_msamp + n * 16 + g * 4);
#pragma unroll
        for (int kk = 0; kk < 4; ++kk)
            wa[n][kk] = *(const bf16x8*)(Wsa_t + (n * 16 + j15) * 128 + kk * 32 + g * 8);
    }

#pragma unroll
    for (int t = 0; t < 4; ++t) {
        const int row = t * 16 + j15;
        const int swz = (row & 7) << 4;
        bf16x8 yf[4];
#pragma unroll
        for (int kk = 0; kk < 4; ++kk) {
            const int byte = row * 256 + ((kk * 64 + g * 16) ^ swz);
            yf[kk] = *(const bf16x8_a*)(Y + byte);
        }
        const int node_local = t * 4 + (j15 >> 2);
        const int c = j15 & 3;
        float* obase = out + (size_t)((b * M_TOT + (m_base + node_local)) * C_ + c) * DIM_;
#pragma unroll
        for (int n = 0; n < 4; ++n) {
            f32x4 acc = {0.f, 0.f, 0.f, 0.f};
#pragma unroll
            for (int kk = 0; kk < 4; ++kk)
                acc = __builtin_amdgcn_mfma_f32_16x16x32_bf16(wa[n][kk], yf[kk], acc, 0, 0, 0);
            f32x4 o;
#pragma unroll
            for (int r = 0; r < 4; ++r)
                o[r] = prelu_f(acc[r] + ba[n][r], a_msamp);
            *(f32x4*)(obase + n * 16 + g * 4) = o;
        }
    }
}

extern "C" void kernel_launch(void* const* d_in, const int* in_sizes, int n_in,
                              void* d_out, int out_size, void* d_ws, size_t ws_size,
                              hipStream_t stream)
{
    const float* last    = (const float*)d_in[0];
    const float* sample  = (const float*)d_in[1];
    const int*   child_l = (const int*)d_in[2];
    const int*   child_r = (const int*)d_in[3];
    const int*   child_s = (const int*)d_in[4];
    const float* W_merge = (const float*)d_in[5];
    const float* b_merge = (const float*)d_in[6];
    const float* a_merge = (const float*)d_in[7];
    const float* W_ms    = (const float*)d_in[8];
    const float* b_ms    = (const float*)d_in[9];
    const float* a_ms    = (const float*)d_in[10];
    const float* W_msamp = (const float*)d_in[11];
    const float* b_msamp = (const float*)d_in[12];
    const float* a_msamp = (const float*)d_in[13];
    float* out = (float*)d_out;

    // weights -> col-major bf16 in workspace (96KB)
    hipLaunchKernelGGL(prep_weights, dim3(192), dim3(256), 0, stream,
                       W_merge, W_ms, W_msamp, (__hip_bfloat16*)d_ws);

    // 8192 node-groups of 16 nodes, 4 per 256-thread block
    hipLaunchKernelGGL(encoder_fused, dim3(2048), dim3(256), 0, stream,
                       last, sample, child_l, child_r, child_s,
                       (const __bf16*)d_ws,
                       b_merge, a_merge, b_ms, a_ms, b_msamp, a_msamp, out);
}